// Round 12
// baseline (182.645 us; speedup 1.0000x reference)
//
#include <hip/hip_runtime.h>
#include <hip/hip_fp16.h>

#define DIM 64
#define PCHUNK 2048
#define BSH 9                   // 512 nodes per bucket
#define BNODES (1 << BSH)

// ---------------- helpers: half2 <-> float punning ----------------
__device__ __forceinline__ float2 h2f(unsigned int u) {
    __half2 h = *reinterpret_cast<__half2*>(&u);
    return __half22float2(h);
}
__device__ __forceinline__ unsigned int f2h(float a, float b) {
    __half2 h = __floats2half2_rn(a, b);
    return *reinterpret_cast<unsigned int*>(&h);
}

// ---------------- edge dtype detection (int64 vs int32) ----------------
__device__ __forceinline__ bool edges_are_i64(const unsigned int* w) {
    unsigned int acc = 0;
#pragma unroll
    for (int k = 0; k < 8; ++k) acc |= w[2 * k + 1];
    return acc == 0;
}
__device__ __forceinline__ int ld_edge(const void* raw, bool is64, size_t idx) {
    return is64 ? (int)((const long long*)raw)[idx] : ((const int*)raw)[idx];
}

// ---------------- pass A: partition raw edges into dst-bucket windows -------
__global__ void k_partition(const void* ei_raw, int E, int NB, int CAP,
                            int* __restrict__ bwcnt, uint2* __restrict__ pe,
                            int* __restrict__ edges32) {
    __shared__ int cnt[512], lstart[512], gb[512], lofs[512], psum[256];
    __shared__ uint2 stage[PCHUNK];
    __shared__ int gpos[PCHUNK];
    bool is64 = edges_are_i64((const unsigned int*)ei_raw);
    int base = blockIdx.x * PCHUNK;
    int n = E - base; if (n > PCHUNK) n = PCHUNK;
    int t = threadIdx.x;
    for (int b = t; b < 512; b += 256) { cnt[b] = 0; lofs[b] = 0; }
    __syncthreads();
    int s[8], d[8];
#pragma unroll
    for (int r = 0; r < 8; ++r) {
        int i = r * 256 + t;
        if (i < n) {
            s[r] = ld_edge(ei_raw, is64, (size_t)base + i);
            d[r] = ld_edge(ei_raw, is64, (size_t)E + base + i);
            edges32[base + i] = s[r];
            edges32[E + base + i] = d[r];
            atomicAdd(&cnt[d[r] >> BSH], 1);
        }
    }
    __syncthreads();
    // parallel exclusive scan of cnt[512] with 256 threads (pair trick)
    int a0 = cnt[2 * t], a1 = cnt[2 * t + 1];
    psum[t] = a0 + a1;
    __syncthreads();
    int v = psum[t];
    for (int o = 1; o < 256; o <<= 1) {
        int tv = (t >= o) ? psum[t - o] : 0;
        __syncthreads();
        psum[t] += tv;
        __syncthreads();
    }
    int excl = psum[t] - v;
    lstart[2 * t] = excl;
    lstart[2 * t + 1] = excl + a0;
    __syncthreads();
    for (int b = t; b < NB; b += 256)
        if (cnt[b] > 0) gb[b] = atomicAdd(&bwcnt[b], cnt[b]);
    __syncthreads();
#pragma unroll
    for (int r = 0; r < 8; ++r) {
        int i = r * 256 + t;
        if (i < n) {
            int b = d[r] >> BSH;
            int j = atomicAdd(&lofs[b], 1);
            int slot = lstart[b] + j;
            stage[slot] = make_uint2((unsigned)s[r], (unsigned)d[r]);
            int gj = gb[b] + j;
            gpos[slot] = (gj < CAP) ? (b * CAP + gj) : (NB * CAP + slot);
        }
    }
    __syncthreads();
    for (int i = t; i < n; i += 256)
        pe[gpos[i]] = stage[i];
}

// ---------------- pass B: per-bucket rowptr/dinv/esrc + y0/embh + nperm -----
__global__ void k_bucket(const uint2* __restrict__ pe, const int* __restrict__ bwcnt,
                         int CAP, int* __restrict__ rowptr, float* __restrict__ dinv,
                         int* __restrict__ esrc, const float* __restrict__ emb,
                         __half* __restrict__ y0h, __half* __restrict__ embh,
                         int* __restrict__ nperm, int N, int E, int NB) {
    __shared__ int ldeg[BNODES], lcur[BNODES], psum[256];
    __shared__ float fdi[BNODES];
    __shared__ int s_eb;
    __shared__ int hist[64], hcur[64];
    int b = blockIdx.x;
    int n0 = b << BSH;
    int nn = N - n0; if (nn > BNODES) nn = BNODES;
    int ecnt = bwcnt[b];
    const uint2* win = pe + (size_t)b * CAP;
    int t = threadIdx.x;
    // inlined bucket-base: eb = sum(bwcnt[0..b))
    int part = 0;
    for (int j = t; j < b; j += 256) part += bwcnt[j];
    psum[t] = part;
    __syncthreads();
    for (int o = 1; o < 256; o <<= 1) {
        int tv = (t >= o) ? psum[t - o] : 0;
        __syncthreads();
        psum[t] += tv;
        __syncthreads();
    }
    if (t == 255) s_eb = psum[255];
    for (int j = t; j < BNODES; j += 256) ldeg[j] = 0;
    if (t < 64) hist[t] = 0;
    __syncthreads();
    int eb = s_eb;
    for (int i = t; i < ecnt; i += 256)
        atomicAdd(&ldeg[win[i].y - n0], 1);
    __syncthreads();
    int a0 = ldeg[2 * t], a1 = ldeg[2 * t + 1];
    psum[t] = a0 + a1;
    __syncthreads();
    int v = psum[t];
    for (int o = 1; o < 256; o <<= 1) {
        int tv = (t >= o) ? psum[t - o] : 0;
        __syncthreads();
        psum[t] += tv;
        __syncthreads();
    }
    int excl = psum[t] - v;
    float d0 = a0 > 0 ? 1.0f / sqrtf((float)a0) : 0.0f;
    float d1 = a1 > 0 ? 1.0f / sqrtf((float)a1) : 0.0f;
    lcur[2 * t] = excl;
    lcur[2 * t + 1] = excl + a0;
    fdi[2 * t] = d0;
    fdi[2 * t + 1] = d1;
    if (2 * t < nn)     { rowptr[n0 + 2 * t] = eb + excl;          dinv[n0 + 2 * t] = d0; }
    if (2 * t + 1 < nn) { rowptr[n0 + 2 * t + 1] = eb + excl + a0; dinv[n0 + 2 * t + 1] = d1; }
    if (b == NB - 1 && t == 0) rowptr[N] = E;
    __syncthreads();
    for (int i = t; i < ecnt; i += 256) {
        uint2 rec = win[i];
        int pos = eb + atomicAdd(&lcur[rec.y - n0], 1);
        esrc[pos] = (int)rec.x;
    }
    // ---- within-bucket degree counting-sort -> nperm (wave balance) ----
    for (int j = t; j < nn; j += 256)
        atomicAdd(&hist[min(ldeg[j], 63)], 1);
    __syncthreads();
    if (t == 0) {
        int run = 0;
        for (int k = 0; k < 64; ++k) { hcur[k] = run; run += hist[k]; }
    }
    __syncthreads();
    for (int j = t; j < nn; j += 256) {
        int pos = atomicAdd(&hcur[min(ldeg[j], 63)], 1);
        nperm[n0 + pos] = n0 + j;
    }
    // fused: y0 = fp16(dinv*emb), embh = fp16(emb) for this bucket (coalesced)
    for (int idx = t; idx < nn * 8; idx += 256) {
        int node = idx >> 3, c = idx & 7;
        float di = fdi[node];
        const float4* p = (const float4*)(emb + (size_t)(n0 + node) * DIM + c * 8);
        float4 a = p[0], bb = p[1];
        uint4 oy, oe;
        oy.x = f2h(di * a.x, di * a.y);   oy.y = f2h(di * a.z, di * a.w);
        oy.z = f2h(di * bb.x, di * bb.y); oy.w = f2h(di * bb.z, di * bb.w);
        oe.x = f2h(a.x, a.y);   oe.y = f2h(a.z, a.w);
        oe.z = f2h(bb.x, bb.y); oe.w = f2h(bb.z, bb.w);
        ((uint4*)(y0h + (size_t)(n0 + node) * DIM))[c] = oy;
        ((uint4*)(embh + (size_t)(n0 + node) * DIM))[c] = oe;
    }
}

// ---------------- accumulate helper ----------------
__device__ __forceinline__ void acc_row(float* acc, uint4 u) {
    float2 f0 = h2f(u.x), f1 = h2f(u.y), f2 = h2f(u.z), f3 = h2f(u.w);
    acc[0] += f0.x; acc[1] += f0.y; acc[2] += f1.x; acc[3] += f1.y;
    acc[4] += f2.x; acc[5] += f2.y; acc[6] += f3.x; acc[7] += f3.y;
}

// ---------------- propagation: ynext = fp16(dinv^2 * sum y[src]) ------------
// 8 threads per node, nodes in degree-sorted (wave-balanced) order.
__global__ void k_prop(const int* __restrict__ rowptr, const int* __restrict__ esrc,
                       const float* __restrict__ dinv, const int* __restrict__ nperm,
                       const __half* __restrict__ ycur, __half* __restrict__ ynext, int N) {
    int t = blockIdx.x * blockDim.x + threadIdx.x;
    int g = t >> 3, c = t & 7;
    if (g >= N) return;
    int node = nperm[g];
    float di = dinv[node];
    int beg = rowptr[node], end = rowptr[node + 1];
    float acc[8] = {0.f, 0.f, 0.f, 0.f, 0.f, 0.f, 0.f, 0.f};
    int i = beg;
    for (; i + 3 < end; i += 4) {
        int s0 = esrc[i], s1 = esrc[i + 1], s2 = esrc[i + 2], s3 = esrc[i + 3];
        uint4 u0 = ((const uint4*)(ycur + (size_t)s0 * DIM))[c];
        uint4 u1 = ((const uint4*)(ycur + (size_t)s1 * DIM))[c];
        uint4 u2 = ((const uint4*)(ycur + (size_t)s2 * DIM))[c];
        uint4 u3 = ((const uint4*)(ycur + (size_t)s3 * DIM))[c];
        acc_row(acc, u0); acc_row(acc, u1); acc_row(acc, u2); acc_row(acc, u3);
    }
    for (; i < end; ++i) {
        int s = esrc[i];
        uint4 u = ((const uint4*)(ycur + (size_t)s * DIM))[c];
        acc_row(acc, u);
    }
    float d2 = di * di;
    uint4 o;
    o.x = f2h(d2 * acc[0], d2 * acc[1]); o.y = f2h(d2 * acc[2], d2 * acc[3]);
    o.z = f2h(d2 * acc[4], d2 * acc[5]); o.w = f2h(d2 * acc[6], d2 * acc[7]);
    ((uint4*)(ynext + (size_t)node * DIM))[c] = o;
}

// ---- last layer: outh = fp16(a0*emb + sd*(a1*y1 + a2*y2) + a3*di*S3) -------
__global__ void k_outp(const int* __restrict__ rowptr, const int* __restrict__ esrc,
                       const float* __restrict__ dinv, const int* __restrict__ nperm,
                       const __half* __restrict__ y2h, const __half* __restrict__ y1h,
                       const __half* __restrict__ embh, const float* __restrict__ alpha,
                       __half* __restrict__ outh, int N) {
    int t = blockIdx.x * blockDim.x + threadIdx.x;
    int g = t >> 3, c = t & 7;
    if (g >= N) return;
    int node = nperm[g];
    float di = dinv[node];
    int beg = rowptr[node], end = rowptr[node + 1];
    float acc[8] = {0.f, 0.f, 0.f, 0.f, 0.f, 0.f, 0.f, 0.f};
    int i = beg;
    for (; i + 3 < end; i += 4) {
        int s0 = esrc[i], s1 = esrc[i + 1], s2 = esrc[i + 2], s3 = esrc[i + 3];
        uint4 u0 = ((const uint4*)(y2h + (size_t)s0 * DIM))[c];
        uint4 u1 = ((const uint4*)(y2h + (size_t)s1 * DIM))[c];
        uint4 u2 = ((const uint4*)(y2h + (size_t)s2 * DIM))[c];
        uint4 u3 = ((const uint4*)(y2h + (size_t)s3 * DIM))[c];
        acc_row(acc, u0); acc_row(acc, u1); acc_row(acc, u2); acc_row(acc, u3);
    }
    for (; i < end; ++i) {
        int s = esrc[i];
        uint4 u = ((const uint4*)(y2h + (size_t)s * DIM))[c];
        acc_row(acc, u);
    }
    float sd = di > 0.f ? 1.0f / di : 0.0f;   // sqrt(deg)
    float a0 = alpha[0], a1 = alpha[1], a2 = alpha[2], a3 = alpha[3];
    uint4 ue = ((const uint4*)(embh + (size_t)node * DIM))[c];
    uint4 u1v = ((const uint4*)(y1h + (size_t)node * DIM))[c];
    uint4 u2v = ((const uint4*)(y2h + (size_t)node * DIM))[c];
    float2 e0 = h2f(ue.x), e1 = h2f(ue.y), e2 = h2f(ue.z), e3 = h2f(ue.w);
    float2 p0 = h2f(u1v.x), p1 = h2f(u1v.y), p2 = h2f(u1v.z), p3 = h2f(u1v.w);
    float2 q0 = h2f(u2v.x), q1 = h2f(u2v.y), q2 = h2f(u2v.z), q3 = h2f(u2v.w);
    float a3d = a3 * di;
    float o[8];
    o[0] = a0 * e0.x + sd * (a1 * p0.x + a2 * q0.x) + a3d * acc[0];
    o[1] = a0 * e0.y + sd * (a1 * p0.y + a2 * q0.y) + a3d * acc[1];
    o[2] = a0 * e1.x + sd * (a1 * p1.x + a2 * q1.x) + a3d * acc[2];
    o[3] = a0 * e1.y + sd * (a1 * p1.y + a2 * q1.y) + a3d * acc[3];
    o[4] = a0 * e2.x + sd * (a1 * p2.x + a2 * q2.x) + a3d * acc[4];
    o[5] = a0 * e2.y + sd * (a1 * p2.y + a2 * q2.y) + a3d * acc[5];
    o[6] = a0 * e3.x + sd * (a1 * p3.x + a2 * q3.x) + a3d * acc[6];
    o[7] = a0 * e3.y + sd * (a1 * p3.y + a2 * q3.y) + a3d * acc[7];
    uint4 u;
    u.x = f2h(o[0], o[1]); u.y = f2h(o[2], o[3]);
    u.z = f2h(o[4], o[5]); u.w = f2h(o[6], o[7]);
    ((uint4*)(outh + (size_t)node * DIM))[c] = u;
}

// ---------------- final: 2 edges per 8-lane group (4-deep MLP) --------------
__global__ void k_final_h2(const int* __restrict__ edges32, const __half* __restrict__ outh,
                           float* __restrict__ res, int E) {
    int t = blockIdx.x * blockDim.x + threadIdx.x;
    int g = t >> 3, c = t & 7;
    int e0 = 2 * g, e1 = 2 * g + 1;
    if (e0 >= E) return;
    bool has1 = (e1 < E);
    int s0 = edges32[e0];
    int d0 = edges32[E + e0];
    int s1 = has1 ? edges32[e1] : s0;
    int d1 = has1 ? edges32[E + e1] : d0;
    uint4 ua0 = ((const uint4*)(outh + (size_t)s0 * DIM))[c];
    uint4 ub0 = ((const uint4*)(outh + (size_t)d0 * DIM))[c];
    uint4 ua1 = ((const uint4*)(outh + (size_t)s1 * DIM))[c];
    uint4 ub1 = ((const uint4*)(outh + (size_t)d1 * DIM))[c];
    float2 a0 = h2f(ua0.x), a1 = h2f(ua0.y), a2 = h2f(ua0.z), a3 = h2f(ua0.w);
    float2 b0 = h2f(ub0.x), b1 = h2f(ub0.y), b2 = h2f(ub0.z), b3 = h2f(ub0.w);
    float p0 = a0.x * b0.x + a0.y * b0.y + a1.x * b1.x + a1.y * b1.y +
               a2.x * b2.x + a2.y * b2.y + a3.x * b3.x + a3.y * b3.y;
    float2 c0 = h2f(ua1.x), c1 = h2f(ua1.y), c2 = h2f(ua1.z), c3 = h2f(ua1.w);
    float2 f0 = h2f(ub1.x), f1 = h2f(ub1.y), f2 = h2f(ub1.z), f3 = h2f(ub1.w);
    float p1 = c0.x * f0.x + c0.y * f0.y + c1.x * f1.x + c1.y * f1.y +
               c2.x * f2.x + c2.y * f2.y + c3.x * f3.x + c3.y * f3.y;
    p0 += __shfl_down(p0, 4, 8);
    p1 += __shfl_down(p1, 4, 8);
    p0 += __shfl_down(p0, 2, 8);
    p1 += __shfl_down(p1, 2, 8);
    p0 += __shfl_down(p0, 1, 8);
    p1 += __shfl_down(p1, 1, 8);
    if (c == 0) {
        if (has1) {
            ((float2*)res)[g] = make_float2(p0, p1);
        } else {
            res[e0] = p0;
        }
    }
}

static inline size_t alignUp(size_t x) { return (x + 511) & ~size_t(511); }

extern "C" void kernel_launch(void* const* d_in, const int* in_sizes, int n_in,
                              void* d_out, int out_size, void* d_ws, size_t ws_size,
                              hipStream_t stream) {
    const void*  ei    = d_in[0];
    const float* emb   = (const float*)d_in[1];
    const float* alpha = (const float*)d_in[2];
    float*       res   = (float*)d_out;

    const int E = in_sizes[0] / 2;       // 1,000,000
    const int N = in_sizes[1] / DIM;     // 150,000

    const int NB = (N + BNODES - 1) >> BSH;           // 293
    int cap = (E / NB) * 3 / 2;
    const int CAP = (cap + 1023) & ~1023;             // 5120

    // ---- carve workspace ----
    char* w = (char*)d_ws;
    size_t off = 0;
    int*    bwcnt   = (int*)(w + off);    off = alignUp(off + (size_t)(NB + 1) * sizeof(int));
    float*  dinv    = (float*)(w + off);  off = alignUp(off + (size_t)N * sizeof(float));
    int*    rowptr  = (int*)(w + off);    off = alignUp(off + (size_t)(N + 1) * sizeof(int));
    int*    nperm   = (int*)(w + off);    off = alignUp(off + (size_t)N * sizeof(int));
    int*    esrc    = (int*)(w + off);    off = alignUp(off + (size_t)E * sizeof(int));
    int*    edges32 = (int*)(w + off);    off = alignUp(off + (size_t)2 * E * sizeof(int));
    uint2*  pe      = (uint2*)(w + off);  off = alignUp(off + ((size_t)NB * CAP + PCHUNK) * sizeof(uint2));
    __half* y0h     = (__half*)(w + off); off = alignUp(off + (size_t)N * DIM * sizeof(__half));
    __half* y1h     = (__half*)(w + off); off = alignUp(off + (size_t)N * DIM * sizeof(__half));
    __half* y2h     = (__half*)(w + off); off = alignUp(off + (size_t)N * DIM * sizeof(__half));
    __half* embh    = (__half*)(w + off); off = alignUp(off + (size_t)N * DIM * sizeof(__half));
    __half* outh    = (__half*)(w + off); off = alignUp(off + (size_t)N * DIM * sizeof(__half));
    (void)ws_size;

    const int B = 256;

    hipMemsetAsync(bwcnt, 0, (size_t)(NB + 1) * sizeof(int), stream);

    int npart = (E + PCHUNK - 1) / PCHUNK;
    k_partition<<<npart, 256, 0, stream>>>(ei, E, NB, CAP, bwcnt, pe, edges32);
    k_bucket<<<NB, 256, 0, stream>>>(pe, bwcnt, CAP, rowptr, dinv, esrc,
                                     emb, y0h, embh, nperm, N, E, NB);

    // ---- 3 layers: 8 threads per node, degree-balanced order ----
    long long tN8 = (long long)N * 8;
    int ggrid = (int)((tN8 + B - 1) / B);
    k_prop<<<ggrid, B, 0, stream>>>(rowptr, esrc, dinv, nperm, y0h, y1h, N);
    k_prop<<<ggrid, B, 0, stream>>>(rowptr, esrc, dinv, nperm, y1h, y2h, N);
    k_outp<<<ggrid, B, 0, stream>>>(rowptr, esrc, dinv, nperm, y2h, y1h, embh, alpha, outh, N);

    // ---- final dots: 2 edges per 8-lane group ----
    long long ngroups = (E + 1) / 2;
    long long tG8 = ngroups * 8;
    k_final_h2<<<(int)((tG8 + B - 1) / B), B, 0, stream>>>(edges32, outh, res, E);
}

// Round 13
// 161.725 us; speedup vs baseline: 1.1294x; 1.1294x over previous
//
#include <hip/hip_runtime.h>
#include <hip/hip_fp16.h>

#define DIM 64
#define PCHUNK 2048
#define BSH 9                   // 512 nodes per bucket
#define BNODES (1 << BSH)

// ---------------- helpers: half2 <-> float punning ----------------
__device__ __forceinline__ float2 h2f(unsigned int u) {
    __half2 h = *reinterpret_cast<__half2*>(&u);
    return __half22float2(h);
}
__device__ __forceinline__ unsigned int f2h(float a, float b) {
    __half2 h = __floats2half2_rn(a, b);
    return *reinterpret_cast<unsigned int*>(&h);
}

// ---------------- edge dtype detection (int64 vs int32) ----------------
__device__ __forceinline__ bool edges_are_i64(const unsigned int* w) {
    unsigned int acc = 0;
#pragma unroll
    for (int k = 0; k < 8; ++k) acc |= w[2 * k + 1];
    return acc == 0;
}
__device__ __forceinline__ int ld_edge(const void* raw, bool is64, size_t idx) {
    return is64 ? (int)((const long long*)raw)[idx] : ((const int*)raw)[idx];
}

// ---------------- pass A: partition raw edges into dst-bucket windows -------
// Also emits a compact int32 copy of the edge list (coalesced) for k_final.
__global__ void k_partition(const void* ei_raw, int E, int NB, int CAP,
                            int* __restrict__ bwcnt, uint2* __restrict__ pe,
                            int* __restrict__ edges32) {
    __shared__ int cnt[512], lstart[512], gb[512], lofs[512], psum[256];
    __shared__ uint2 stage[PCHUNK];
    __shared__ int gpos[PCHUNK];
    bool is64 = edges_are_i64((const unsigned int*)ei_raw);
    int base = blockIdx.x * PCHUNK;
    int n = E - base; if (n > PCHUNK) n = PCHUNK;
    int t = threadIdx.x;
    for (int b = t; b < 512; b += 256) { cnt[b] = 0; lofs[b] = 0; }
    __syncthreads();
    int s[8], d[8];
#pragma unroll
    for (int r = 0; r < 8; ++r) {
        int i = r * 256 + t;
        if (i < n) {
            s[r] = ld_edge(ei_raw, is64, (size_t)base + i);
            d[r] = ld_edge(ei_raw, is64, (size_t)E + base + i);
            edges32[base + i] = s[r];
            edges32[E + base + i] = d[r];
            atomicAdd(&cnt[d[r] >> BSH], 1);
        }
    }
    __syncthreads();
    // parallel exclusive scan of cnt[512] with 256 threads (pair trick)
    int a0 = cnt[2 * t], a1 = cnt[2 * t + 1];
    psum[t] = a0 + a1;
    __syncthreads();
    int v = psum[t];
    for (int o = 1; o < 256; o <<= 1) {
        int tv = (t >= o) ? psum[t - o] : 0;
        __syncthreads();
        psum[t] += tv;
        __syncthreads();
    }
    int excl = psum[t] - v;
    lstart[2 * t] = excl;
    lstart[2 * t + 1] = excl + a0;
    __syncthreads();
    for (int b = t; b < NB; b += 256)
        if (cnt[b] > 0) gb[b] = atomicAdd(&bwcnt[b], cnt[b]);
    __syncthreads();
#pragma unroll
    for (int r = 0; r < 8; ++r) {
        int i = r * 256 + t;
        if (i < n) {
            int b = d[r] >> BSH;
            int j = atomicAdd(&lofs[b], 1);
            int slot = lstart[b] + j;
            stage[slot] = make_uint2((unsigned)s[r], (unsigned)d[r]);
            int gj = gb[b] + j;
            gpos[slot] = (gj < CAP) ? (b * CAP + gj) : (NB * CAP + slot);
        }
    }
    __syncthreads();
    for (int i = t; i < n; i += 256)
        pe[gpos[i]] = stage[i];
}

// ---------------- pass B: per-bucket rowptr/dinv/esrc + y0/embh -------------
__global__ void k_bucket(const uint2* __restrict__ pe, const int* __restrict__ bwcnt,
                         int CAP, int* __restrict__ rowptr, float* __restrict__ dinv,
                         int* __restrict__ esrc, const float* __restrict__ emb,
                         __half* __restrict__ y0h, __half* __restrict__ embh,
                         int N, int E, int NB) {
    __shared__ int ldeg[BNODES], lcur[BNODES], psum[256];
    __shared__ float fdi[BNODES];
    __shared__ int s_eb;
    int b = blockIdx.x;
    int n0 = b << BSH;
    int nn = N - n0; if (nn > BNODES) nn = BNODES;
    int ecnt = bwcnt[b];
    const uint2* win = pe + (size_t)b * CAP;
    int t = threadIdx.x;
    // inlined bucket-base: eb = sum(bwcnt[0..b))
    int part = 0;
    for (int j = t; j < b; j += 256) part += bwcnt[j];
    psum[t] = part;
    __syncthreads();
    for (int o = 1; o < 256; o <<= 1) {
        int tv = (t >= o) ? psum[t - o] : 0;
        __syncthreads();
        psum[t] += tv;
        __syncthreads();
    }
    if (t == 255) s_eb = psum[255];
    for (int j = t; j < BNODES; j += 256) ldeg[j] = 0;
    __syncthreads();
    int eb = s_eb;
    for (int i = t; i < ecnt; i += 256)
        atomicAdd(&ldeg[win[i].y - n0], 1);
    __syncthreads();
    int a0 = ldeg[2 * t], a1 = ldeg[2 * t + 1];
    psum[t] = a0 + a1;
    __syncthreads();
    int v = psum[t];
    for (int o = 1; o < 256; o <<= 1) {
        int tv = (t >= o) ? psum[t - o] : 0;
        __syncthreads();
        psum[t] += tv;
        __syncthreads();
    }
    int excl = psum[t] - v;
    float d0 = a0 > 0 ? 1.0f / sqrtf((float)a0) : 0.0f;
    float d1 = a1 > 0 ? 1.0f / sqrtf((float)a1) : 0.0f;
    lcur[2 * t] = excl;
    lcur[2 * t + 1] = excl + a0;
    fdi[2 * t] = d0;
    fdi[2 * t + 1] = d1;
    if (2 * t < nn)     { rowptr[n0 + 2 * t] = eb + excl;          dinv[n0 + 2 * t] = d0; }
    if (2 * t + 1 < nn) { rowptr[n0 + 2 * t + 1] = eb + excl + a0; dinv[n0 + 2 * t + 1] = d1; }
    if (b == NB - 1 && t == 0) rowptr[N] = E;
    __syncthreads();
    for (int i = t; i < ecnt; i += 256) {
        uint2 rec = win[i];
        int pos = eb + atomicAdd(&lcur[rec.y - n0], 1);
        esrc[pos] = (int)rec.x;
    }
    // fused: y0 = fp16(dinv*emb), embh = fp16(emb) for this bucket (coalesced)
    for (int idx = t; idx < nn * 8; idx += 256) {
        int node = idx >> 3, c = idx & 7;
        float di = fdi[node];
        const float4* p = (const float4*)(emb + (size_t)(n0 + node) * DIM + c * 8);
        float4 a = p[0], bb = p[1];
        uint4 oy, oe;
        oy.x = f2h(di * a.x, di * a.y);   oy.y = f2h(di * a.z, di * a.w);
        oy.z = f2h(di * bb.x, di * bb.y); oy.w = f2h(di * bb.z, di * bb.w);
        oe.x = f2h(a.x, a.y);   oe.y = f2h(a.z, a.w);
        oe.z = f2h(bb.x, bb.y); oe.w = f2h(bb.z, bb.w);
        ((uint4*)(y0h + (size_t)(n0 + node) * DIM))[c] = oy;
        ((uint4*)(embh + (size_t)(n0 + node) * DIM))[c] = oe;
    }
}

// ---------------- accumulate helper ----------------
__device__ __forceinline__ void acc_row(float* acc, uint4 u) {
    float2 f0 = h2f(u.x), f1 = h2f(u.y), f2 = h2f(u.z), f3 = h2f(u.w);
    acc[0] += f0.x; acc[1] += f0.y; acc[2] += f1.x; acc[3] += f1.y;
    acc[4] += f2.x; acc[5] += f2.y; acc[6] += f3.x; acc[7] += f3.y;
}

// ---------------- propagation: ynext = fp16(dinv^2 * sum y[src]) ------------
__global__ void k_prop(const int* __restrict__ rowptr, const int* __restrict__ esrc,
                       const float* __restrict__ dinv, const __half* __restrict__ ycur,
                       __half* __restrict__ ynext, int N) {
    int t = blockIdx.x * blockDim.x + threadIdx.x;
    int node = t >> 3, c = t & 7;
    if (node >= N) return;
    float di = dinv[node];
    int beg = rowptr[node], end = rowptr[node + 1];
    float acc[8] = {0.f, 0.f, 0.f, 0.f, 0.f, 0.f, 0.f, 0.f};
    int i = beg;
    for (; i + 3 < end; i += 4) {
        int s0 = esrc[i], s1 = esrc[i + 1], s2 = esrc[i + 2], s3 = esrc[i + 3];
        uint4 u0 = ((const uint4*)(ycur + (size_t)s0 * DIM))[c];
        uint4 u1 = ((const uint4*)(ycur + (size_t)s1 * DIM))[c];
        uint4 u2 = ((const uint4*)(ycur + (size_t)s2 * DIM))[c];
        uint4 u3 = ((const uint4*)(ycur + (size_t)s3 * DIM))[c];
        acc_row(acc, u0); acc_row(acc, u1); acc_row(acc, u2); acc_row(acc, u3);
    }
    for (; i < end; ++i) {
        int s = esrc[i];
        uint4 u = ((const uint4*)(ycur + (size_t)s * DIM))[c];
        acc_row(acc, u);
    }
    float d2 = di * di;
    uint4 o;
    o.x = f2h(d2 * acc[0], d2 * acc[1]); o.y = f2h(d2 * acc[2], d2 * acc[3]);
    o.z = f2h(d2 * acc[4], d2 * acc[5]); o.w = f2h(d2 * acc[6], d2 * acc[7]);
    ((uint4*)(ynext + (size_t)node * DIM))[c] = o;
}

// ---- last layer: outh = fp16(a0*emb + sd*(a1*y1 + a2*y2) + a3*di*S3) -------
__global__ void k_outp(const int* __restrict__ rowptr, const int* __restrict__ esrc,
                       const float* __restrict__ dinv, const __half* __restrict__ y2h,
                       const __half* __restrict__ y1h, const __half* __restrict__ embh,
                       const float* __restrict__ alpha, __half* __restrict__ outh, int N) {
    int t = blockIdx.x * blockDim.x + threadIdx.x;
    int node = t >> 3, c = t & 7;
    if (node >= N) return;
    float di = dinv[node];
    int beg = rowptr[node], end = rowptr[node + 1];
    float acc[8] = {0.f, 0.f, 0.f, 0.f, 0.f, 0.f, 0.f, 0.f};
    int i = beg;
    for (; i + 3 < end; i += 4) {
        int s0 = esrc[i], s1 = esrc[i + 1], s2 = esrc[i + 2], s3 = esrc[i + 3];
        uint4 u0 = ((const uint4*)(y2h + (size_t)s0 * DIM))[c];
        uint4 u1 = ((const uint4*)(y2h + (size_t)s1 * DIM))[c];
        uint4 u2 = ((const uint4*)(y2h + (size_t)s2 * DIM))[c];
        uint4 u3 = ((const uint4*)(y2h + (size_t)s3 * DIM))[c];
        acc_row(acc, u0); acc_row(acc, u1); acc_row(acc, u2); acc_row(acc, u3);
    }
    for (; i < end; ++i) {
        int s = esrc[i];
        uint4 u = ((const uint4*)(y2h + (size_t)s * DIM))[c];
        acc_row(acc, u);
    }
    float sd = di > 0.f ? 1.0f / di : 0.0f;   // sqrt(deg)
    float a0 = alpha[0], a1 = alpha[1], a2 = alpha[2], a3 = alpha[3];
    uint4 ue = ((const uint4*)(embh + (size_t)node * DIM))[c];
    uint4 u1v = ((const uint4*)(y1h + (size_t)node * DIM))[c];
    uint4 u2v = ((const uint4*)(y2h + (size_t)node * DIM))[c];
    float2 e0 = h2f(ue.x), e1 = h2f(ue.y), e2 = h2f(ue.z), e3 = h2f(ue.w);
    float2 p0 = h2f(u1v.x), p1 = h2f(u1v.y), p2 = h2f(u1v.z), p3 = h2f(u1v.w);
    float2 q0 = h2f(u2v.x), q1 = h2f(u2v.y), q2 = h2f(u2v.z), q3 = h2f(u2v.w);
    float a3d = a3 * di;
    float o[8];
    o[0] = a0 * e0.x + sd * (a1 * p0.x + a2 * q0.x) + a3d * acc[0];
    o[1] = a0 * e0.y + sd * (a1 * p0.y + a2 * q0.y) + a3d * acc[1];
    o[2] = a0 * e1.x + sd * (a1 * p1.x + a2 * q1.x) + a3d * acc[2];
    o[3] = a0 * e1.y + sd * (a1 * p1.y + a2 * q1.y) + a3d * acc[3];
    o[4] = a0 * e2.x + sd * (a1 * p2.x + a2 * q2.x) + a3d * acc[4];
    o[5] = a0 * e2.y + sd * (a1 * p2.y + a2 * q2.y) + a3d * acc[5];
    o[6] = a0 * e3.x + sd * (a1 * p3.x + a2 * q3.x) + a3d * acc[6];
    o[7] = a0 * e3.y + sd * (a1 * p3.y + a2 * q3.y) + a3d * acc[7];
    uint4 u;
    u.x = f2h(o[0], o[1]); u.y = f2h(o[2], o[3]);
    u.z = f2h(o[4], o[5]); u.w = f2h(o[6], o[7]);
    ((uint4*)(outh + (size_t)node * DIM))[c] = u;
}

// ---------------- final: 2 edges per 8-lane group (4-deep MLP) --------------
__global__ void k_final_h2(const int* __restrict__ edges32, const __half* __restrict__ outh,
                           float* __restrict__ res, int E) {
    int t = blockIdx.x * blockDim.x + threadIdx.x;
    int g = t >> 3, c = t & 7;
    int e0 = 2 * g, e1 = 2 * g + 1;
    if (e0 >= E) return;
    bool has1 = (e1 < E);
    int s0 = edges32[e0];
    int d0 = edges32[E + e0];
    int s1 = has1 ? edges32[e1] : s0;
    int d1 = has1 ? edges32[E + e1] : d0;
    uint4 ua0 = ((const uint4*)(outh + (size_t)s0 * DIM))[c];
    uint4 ub0 = ((const uint4*)(outh + (size_t)d0 * DIM))[c];
    uint4 ua1 = ((const uint4*)(outh + (size_t)s1 * DIM))[c];
    uint4 ub1 = ((const uint4*)(outh + (size_t)d1 * DIM))[c];
    float2 a0 = h2f(ua0.x), a1 = h2f(ua0.y), a2 = h2f(ua0.z), a3 = h2f(ua0.w);
    float2 b0 = h2f(ub0.x), b1 = h2f(ub0.y), b2 = h2f(ub0.z), b3 = h2f(ub0.w);
    float p0 = a0.x * b0.x + a0.y * b0.y + a1.x * b1.x + a1.y * b1.y +
               a2.x * b2.x + a2.y * b2.y + a3.x * b3.x + a3.y * b3.y;
    float2 c0 = h2f(ua1.x), c1 = h2f(ua1.y), c2 = h2f(ua1.z), c3 = h2f(ua1.w);
    float2 f0 = h2f(ub1.x), f1 = h2f(ub1.y), f2 = h2f(ub1.z), f3 = h2f(ub1.w);
    float p1 = c0.x * f0.x + c0.y * f0.y + c1.x * f1.x + c1.y * f1.y +
               c2.x * f2.x + c2.y * f2.y + c3.x * f3.x + c3.y * f3.y;
    p0 += __shfl_down(p0, 4, 8);
    p1 += __shfl_down(p1, 4, 8);
    p0 += __shfl_down(p0, 2, 8);
    p1 += __shfl_down(p1, 2, 8);
    p0 += __shfl_down(p0, 1, 8);
    p1 += __shfl_down(p1, 1, 8);
    if (c == 0) {
        if (has1) {
            ((float2*)res)[g] = make_float2(p0, p1);
        } else {
            res[e0] = p0;
        }
    }
}

static inline size_t alignUp(size_t x) { return (x + 511) & ~size_t(511); }

extern "C" void kernel_launch(void* const* d_in, const int* in_sizes, int n_in,
                              void* d_out, int out_size, void* d_ws, size_t ws_size,
                              hipStream_t stream) {
    const void*  ei    = d_in[0];
    const float* emb   = (const float*)d_in[1];
    const float* alpha = (const float*)d_in[2];
    float*       res   = (float*)d_out;

    const int E = in_sizes[0] / 2;       // 1,000,000
    const int N = in_sizes[1] / DIM;     // 150,000

    const int NB = (N + BNODES - 1) >> BSH;           // 293
    int cap = (E / NB) * 3 / 2;
    const int CAP = (cap + 1023) & ~1023;             // 5120

    // ---- carve workspace ----
    char* w = (char*)d_ws;
    size_t off = 0;
    int*    bwcnt   = (int*)(w + off);    off = alignUp(off + (size_t)(NB + 1) * sizeof(int));
    float*  dinv    = (float*)(w + off);  off = alignUp(off + (size_t)N * sizeof(float));
    int*    rowptr  = (int*)(w + off);    off = alignUp(off + (size_t)(N + 1) * sizeof(int));
    int*    esrc    = (int*)(w + off);    off = alignUp(off + (size_t)E * sizeof(int));
    int*    edges32 = (int*)(w + off);    off = alignUp(off + (size_t)2 * E * sizeof(int));
    uint2*  pe      = (uint2*)(w + off);  off = alignUp(off + ((size_t)NB * CAP + PCHUNK) * sizeof(uint2));
    __half* y0h     = (__half*)(w + off); off = alignUp(off + (size_t)N * DIM * sizeof(__half));
    __half* y1h     = (__half*)(w + off); off = alignUp(off + (size_t)N * DIM * sizeof(__half));
    __half* y2h     = (__half*)(w + off); off = alignUp(off + (size_t)N * DIM * sizeof(__half));
    __half* embh    = (__half*)(w + off); off = alignUp(off + (size_t)N * DIM * sizeof(__half));
    __half* outh    = (__half*)(w + off); off = alignUp(off + (size_t)N * DIM * sizeof(__half));
    (void)ws_size;

    const int B = 256;

    hipMemsetAsync(bwcnt, 0, (size_t)(NB + 1) * sizeof(int), stream);

    int npart = (E + PCHUNK - 1) / PCHUNK;
    k_partition<<<npart, 256, 0, stream>>>(ei, E, NB, CAP, bwcnt, pe, edges32);
    k_bucket<<<NB, 256, 0, stream>>>(pe, bwcnt, CAP, rowptr, dinv, esrc,
                                     emb, y0h, embh, N, E, NB);

    // ---- 3 layers: 8 threads per node, unroll-4 pipelined edge loop ----
    long long tN8 = (long long)N * 8;
    int ggrid = (int)((tN8 + B - 1) / B);
    k_prop<<<ggrid, B, 0, stream>>>(rowptr, esrc, dinv, y0h, y1h, N);
    k_prop<<<ggrid, B, 0, stream>>>(rowptr, esrc, dinv, y1h, y2h, N);
    k_outp<<<ggrid, B, 0, stream>>>(rowptr, esrc, dinv, y2h, y1h, embh, alpha, outh, N);

    // ---- final dots: 2 edges per 8-lane group ----
    long long ngroups = (E + 1) / 2;
    long long tG8 = ngroups * 8;
    k_final_h2<<<(int)((tG8 + B - 1) / B), B, 0, stream>>>(edges32, outh, res, E);
}